// Round 16
// baseline (646.492 us; speedup 1.0000x reference)
//
#include <hip/hip_runtime.h>

typedef unsigned int u32;
typedef float f32x4 __attribute__((ext_vector_type(4)));
typedef _Float16 f16x8 __attribute__((ext_vector_type(8)));
typedef _Float16 f16x4 __attribute__((ext_vector_type(4)));
typedef _Float16 f16x2 __attribute__((ext_vector_type(2)));

static constexpr int kN = 500000;   // points
static constexpr int kC = 10000;    // clusters

// monotone float<->uint encoding so atomicMax(u32) == float max
__device__ __forceinline__ u32 fenc(float f) {
  int b = __float_as_int(f);
  return (b >= 0) ? ((u32)b | 0x80000000u) : ~((u32)b);
}
__device__ __forceinline__ float fdec(u32 u) {
  int b = (u & 0x80000000u) ? (int)(u & 0x7FFFFFFFu) : (int)(~u);
  return __int_as_float(b);
}

// ---------- W -> f16 concat + bias + WkT + histogram + q_enc zero (fused) ----------
__global__ void k_wcvt(const float* __restrict__ Wv, const float* __restrict__ Wk,
                       const float* __restrict__ Wq, const float* __restrict__ bv,
                       const float* __restrict__ bk, const float* __restrict__ bq,
                       _Float16* __restrict__ Wc, float* __restrict__ bias_c,
                       _Float16* __restrict__ WkT, const int* __restrict__ cluster,
                       int* __restrict__ hist, u32* __restrict__ q_enc) {
  const int i = blockIdx.x * blockDim.x + threadIdx.x;
  const long stride = (long)gridDim.x * blockDim.x;
  if (i < 384) bias_c[i] = (i < 128) ? bv[i] : (i < 256) ? bk[i - 128] : bq[i - 256];
  if (i < 128 * 128) {  // WkT[d][j] = Wk[j][d]
    int d = i >> 7, j = i & 127;
    WkT[i] = (_Float16)Wk[j * 128 + d];
  }
  if (i < 384 * 128) {
    int row = i >> 7;
    float f = (row < 128) ? Wv[i] : (row < 256) ? Wk[i - 128 * 128] : Wq[i - 256 * 128];
    Wc[i] = (_Float16)f;
  }
  // q_enc zero (encoded 0 == below -inf for the atomicMax)
  for (long e = i; e < (long)kC * 128; e += stride) q_enc[e] = 0u;
  // grid-stride histogram
  for (long n = i; n < kN; n += stride) atomicAdd(hist + cluster[n], 1);
}

// ---------- counting sort by cluster ----------
__global__ void k_scan(const int* __restrict__ hist, int* __restrict__ offs,
                       int* __restrict__ cur) {
  __shared__ int sh[256];
  const int t = threadIdx.x;  // 256 threads
  const int b0 = t * 40;
  const int e0 = (b0 + 40 < kC) ? b0 + 40 : kC;
  int s = 0;
  for (int i = b0; i < e0; ++i) s += hist[i];
  sh[t] = s;
  __syncthreads();
  for (int d = 1; d < 256; d <<= 1) {
    int v = (t >= d) ? sh[t - d] : 0;
    __syncthreads();
    sh[t] += v;
    __syncthreads();
  }
  int run = sh[t] - s;  // exclusive prefix
  for (int i = b0; i < e0; ++i) {
    offs[i] = run;
    cur[i] = run;
    run += hist[i];
  }
}

__global__ void k_scatter(const int* __restrict__ cluster, int* __restrict__ cur,
                          int* __restrict__ order, int* __restrict__ csort) {
  int n = blockIdx.x * blockDim.x + threadIdx.x;
  if (n < kN) {
    int c = cluster[n];
    int pos = atomicAdd(cur + c, 1);
    order[pos] = n;
    csort[pos] = c;
  }
}

// ---------- v-projection + x->f16, ALL NATURAL STREAMING ----------
// Wave owns 64 consecutive natural points; reads x f32 streaming, writes
// v_nat (8 m-tiles of Wv) and x_nat (f16 copy) streaming. Zero gathers.
__global__ __launch_bounds__(256, 4) void k_vproj(
    const float* __restrict__ x, const _Float16* __restrict__ Wc,
    const float* __restrict__ bias_c, _Float16* __restrict__ v_nat,
    _Float16* __restrict__ x_nat) {
  __shared__ _Float16 stg[4][64][70];
  const int lane = threadIdx.x & 63, wid = threadIdx.x >> 6;
  const int g = lane >> 4, r = lane & 15;
  const long pbase = (long)blockIdx.x * 256 + wid * 64;

  f16x8 xf[4][4];
#pragma unroll
  for (int p = 0; p < 4; ++p) {
    long row = pbase + p * 16 + r;
    if (row >= kN) row = kN - 1;
    const float* xp = x + row * 128;
#pragma unroll
    for (int kk = 0; kk < 4; ++kk) {
      float4 f0 = *(const float4*)(xp + kk * 32 + g * 8);
      float4 f1 = *(const float4*)(xp + kk * 32 + g * 8 + 4);
      f16x8 h;
      h[0] = (_Float16)f0.x; h[1] = (_Float16)f0.y;
      h[2] = (_Float16)f0.z; h[3] = (_Float16)f0.w;
      h[4] = (_Float16)f1.x; h[5] = (_Float16)f1.y;
      h[6] = (_Float16)f1.z; h[7] = (_Float16)f1.w;
      xf[p][kk] = h;
    }
  }

  // stage + flush x_nat (f16, natural, streaming), two 64-dim halves
#pragma unroll
  for (int h = 0; h < 2; ++h) {
#pragma unroll
    for (int p = 0; p < 4; ++p) {
#pragma unroll
      for (int q2 = 0; q2 < 2; ++q2)
        *(f16x8*)&stg[wid][p * 16 + r][q2 * 32 + g * 8] = xf[p][2 * h + q2];
    }
    const int off = h * 64;
#pragma unroll
    for (int s = 0; s < 8; ++s) {
      const int pl = 8 * s + (lane >> 3);
      const long pt = pbase + pl;
      if (pt < kN) {
        f16x8 val = *(const f16x8*)&stg[wid][pl][(lane & 7) * 8];
        *(f16x8*)(x_nat + pt * 128 + off + (lane & 7) * 8) = val;
      }
    }
  }

  // v tiles (Wv = Wc tiles 0..7), two 64-dim groups
#pragma unroll
  for (int mg = 0; mg < 2; ++mg) {
#pragma unroll
    for (int mu = 0; mu < 4; ++mu) {
      const int mt = mg * 4 + mu;
      const _Float16* wrow = Wc + (mt * 16 + r) * 128;
      f16x8 wf[4];
#pragma unroll
      for (int kk = 0; kk < 4; ++kk)
        wf[kk] = *(const f16x8*)(wrow + kk * 32 + g * 8);
      float4 b4 = *(const float4*)(bias_c + mt * 16 + g * 4);
#pragma unroll
      for (int p = 0; p < 4; ++p) {
        f32x4 acc = {0.f, 0.f, 0.f, 0.f};
#pragma unroll
        for (int kk = 0; kk < 4; ++kk)
          acc = __builtin_amdgcn_mfma_f32_16x16x32_f16(wf[kk], xf[p][kk], acc, 0, 0, 0);
        f16x4 h;
        h[0] = (_Float16)(acc[0] + b4.x);
        h[1] = (_Float16)(acc[1] + b4.y);
        h[2] = (_Float16)(acc[2] + b4.z);
        h[3] = (_Float16)(acc[3] + b4.w);
        *(f16x4*)&stg[wid][p * 16 + r][mu * 16 + g * 4] = h;
      }
    }
    const int off = mg * 64;
#pragma unroll
    for (int s = 0; s < 8; ++s) {
      const int pl = 8 * s + (lane >> 3);
      const long pt = pbase + pl;
      if (pt < kN) {
        f16x8 val = *(const f16x8*)&stg[wid][pl][(lane & 7) * 8];
        *(f16x8*)(v_nat + pt * 128 + off + (lane & 7) * 8) = val;
      }
    }
  }
}

// ---------- q-projection in SORTED domain (gathers L3-resident x_nat f16) ----------
// Only the 8 Wq tiles; qp reduced over sorted cluster-runs -> atomicMax(q_enc).
__global__ __launch_bounds__(256, 2) void k_qproj(
    const _Float16* __restrict__ x_nat, const int* __restrict__ order,
    const int* __restrict__ csort, const _Float16* __restrict__ Wc,
    const float* __restrict__ bias_c, u32* __restrict__ q_enc) {
  __shared__ _Float16 stg[4][64][70];
  const int lane = threadIdx.x & 63, wid = threadIdx.x >> 6;
  const int g = lane >> 4, r = lane & 15;
  const long pbase = (long)blockIdx.x * 256 + wid * 64;

  long mypos = pbase + lane;
  if (mypos >= kN) mypos = kN - 1;
  const int myc = csort[mypos];

  // gather x_nat f16 rows (256B each, L3-resident right after k_vproj)
  f16x8 xq[4][4];
#pragma unroll
  for (int p = 0; p < 4; ++p) {
    long pos = pbase + p * 16 + r;
    if (pos >= kN) pos = kN - 1;
    const _Float16* xp = x_nat + (long)order[pos] * 128;
#pragma unroll
    for (int kk = 0; kk < 4; ++kk)
      xq[p][kk] = *(const f16x8*)(xp + kk * 32 + g * 8);
  }

#pragma unroll
  for (int mg = 0; mg < 2; ++mg) {  // two 64-dim halves of q
#pragma unroll
    for (int mu = 0; mu < 4; ++mu) {
      const int mt = 16 + mg * 4 + mu;  // Wq tiles 16..23
      const _Float16* wrow = Wc + (mt * 16 + r) * 128;
      f16x8 wf[4];
#pragma unroll
      for (int kk = 0; kk < 4; ++kk)
        wf[kk] = *(const f16x8*)(wrow + kk * 32 + g * 8);
      float4 b4 = *(const float4*)(bias_c + mt * 16 + g * 4);
#pragma unroll
      for (int p = 0; p < 4; ++p) {
        f32x4 acc = {0.f, 0.f, 0.f, 0.f};
#pragma unroll
        for (int kk = 0; kk < 4; ++kk)
          acc = __builtin_amdgcn_mfma_f32_16x16x32_f16(wf[kk], xq[p][kk], acc, 0, 0, 0);
        f16x4 h;
        h[0] = (_Float16)(acc[0] + b4.x);
        h[1] = (_Float16)(acc[1] + b4.y);
        h[2] = (_Float16)(acc[2] + b4.z);
        h[3] = (_Float16)(acc[3] + b4.w);
        *(f16x4*)&stg[wid][p * 16 + r][mu * 16 + g * 4] = h;
      }
    }
    // per-dim run-max scan over the wave's 64 sorted points
    const int dg = mg * 64 + lane;
    float m = -3.0e38f;
    int cprev = __shfl(myc, 0);
    for (int i = 0; i < 64; ++i) {
      int ci = __shfl(myc, i);
      if (ci != cprev) {  // wave-uniform branch
        atomicMax(q_enc + (long)cprev * 128 + dg, fenc(m));
        m = -3.0e38f;
        cprev = ci;
      }
      m = fmaxf(m, (float)stg[wid][i][lane]);
    }
    atomicMax(q_enc + (long)cprev * 128 + dg, fenc(m));
  }
}

// ---------- w_all[c][j] = (Wk^T q_c)[j]  (tiny MFMA GEMM) ----------
__global__ __launch_bounds__(256) void k_wq(const u32* __restrict__ q_enc,
                                            const _Float16* __restrict__ WkT,
                                            float* __restrict__ w_all) {
  __shared__ float wt[4][16][132];
  const int lane = threadIdx.x & 63, wid = threadIdx.x >> 6;
  const int g = lane >> 4, r = lane & 15;
  const int c0 = blockIdx.x * 64 + wid * 16;

  f16x8 qb[4];
  {
    int crow = c0 + r;
    if (crow >= kC) crow = kC - 1;
    const u32* qp = q_enc + (long)crow * 128;
#pragma unroll
    for (int kk = 0; kk < 4; ++kk) {
      uint4 u0 = *(const uint4*)(qp + kk * 32 + g * 8);
      uint4 u1 = *(const uint4*)(qp + kk * 32 + g * 8 + 4);
      f16x8 h;
      h[0] = (_Float16)fdec(u0.x); h[1] = (_Float16)fdec(u0.y);
      h[2] = (_Float16)fdec(u0.z); h[3] = (_Float16)fdec(u0.w);
      h[4] = (_Float16)fdec(u1.x); h[5] = (_Float16)fdec(u1.y);
      h[6] = (_Float16)fdec(u1.z); h[7] = (_Float16)fdec(u1.w);
      qb[kk] = h;
    }
  }
#pragma unroll
  for (int dt = 0; dt < 8; ++dt) {
    f32x4 acc = {0.f, 0.f, 0.f, 0.f};
#pragma unroll
    for (int kk = 0; kk < 4; ++kk) {
      f16x8 af = *(const f16x8*)(WkT + (dt * 16 + r) * 128 + kk * 32 + g * 8);
      acc = __builtin_amdgcn_mfma_f32_16x16x32_f16(af, qb[kk], acc, 0, 0, 0);
    }
#pragma unroll
    for (int jj = 0; jj < 4; ++jj)
      wt[wid][r][dt * 16 + g * 4 + jj] = acc[jj];
  }
#pragma unroll
  for (int s = 0; s < 8; ++s) {
    int row = s * 2 + (lane >> 5);
    int col = (lane & 31) * 4;
    int c = c0 + row;
    if (c < kC) {
      float4 v = *(const float4*)&wt[wid][row][col];
      *(float4*)(w_all + (long)c * 128 + col) = v;
    }
  }
}

// ---------- M[n] = x_nat[n].w_all[c_n] (stream x, cached w); m = seg max ----------
__global__ __launch_bounds__(256) void k_m(
    const _Float16* __restrict__ x_nat, const float* __restrict__ w_all,
    const int* __restrict__ cluster, float* __restrict__ M_nat,
    u32* __restrict__ m_enc) {
  const int t = threadIdx.x, grp = t >> 4, sl = t & 15;
  long n = (long)blockIdx.x * 16 + grp;
  if (n >= kN) return;
  int c = cluster[n];
  f16x8 hx = *(const f16x8*)(x_nat + n * 128 + sl * 8);
  const float* wp = w_all + (long)c * 128 + sl * 8;
  float4 w0 = *(const float4*)wp;
  float4 w1 = *(const float4*)(wp + 4);
  float p = (float)hx[0] * w0.x + (float)hx[1] * w0.y +
            (float)hx[2] * w0.z + (float)hx[3] * w0.w +
            (float)hx[4] * w1.x + (float)hx[5] * w1.y +
            (float)hx[6] * w1.z + (float)hx[7] * w1.w;
  p += __shfl_xor(p, 1, 64);
  p += __shfl_xor(p, 2, 64);
  p += __shfl_xor(p, 4, 64);
  p += __shfl_xor(p, 8, 64);
  if (sl == 0) {
    M_nat[n] = p;
    atomicMax(m_enc + c, fenc(p));
  }
}

// ---------- e = exp(M - m[c]) (stored back into M_nat); s[c] += e ----------
__global__ void k_expsum(float* __restrict__ M_nat, const u32* __restrict__ m_enc,
                         const int* __restrict__ cluster, float* __restrict__ s_sum) {
  long n = (long)blockIdx.x * blockDim.x + threadIdx.x;
  if (n >= kN) return;
  int c = cluster[n];
  float e = __expf(M_nat[n] - fdec(m_enc[c]));
  M_nat[n] = e;
  atomicAdd(s_sum + c, e);
}

// ---------- BN stats: a = e/s[c]; partials of y=a*v, y^2 (streaming) ----------
__global__ __launch_bounds__(256) void k_bnstats(
    const _Float16* __restrict__ v_nat, const float* __restrict__ M_nat,
    const float* __restrict__ s_sum, const int* __restrict__ cluster,
    float* __restrict__ a_nat, float* __restrict__ part_mu,
    float* __restrict__ part_m2) {
  const int t = threadIdx.x;
  const int d2 = (t & 63) * 2, rg = t >> 6;
  float s0 = 0.f, s1 = 0.f, p0 = 0.f, p1 = 0.f;
  for (long base = (long)blockIdx.x * 4; base < kN; base += (long)gridDim.x * 4) {
    long row = base + rg;
    if (row < kN) {
      float a = M_nat[row] / s_sum[cluster[row]];
      if ((t & 63) == 0) a_nat[row] = a;
      f16x2 h = *(const f16x2*)(v_nat + row * 128 + d2);
      float y0 = a * (float)h[0], y1 = a * (float)h[1];
      s0 += y0; s1 += y1; p0 += y0 * y0; p1 += y1 * y1;
    }
  }
  __shared__ float red[1024];
  red[t] = s0; red[t + 256] = s1; red[t + 512] = p0; red[t + 768] = p1;
  __syncthreads();
  if (t < 64) {
    float a0 = red[t] + red[t + 64] + red[t + 128] + red[t + 192];
    float a1 = red[t + 256] + red[t + 320] + red[t + 384] + red[t + 448];
    float b0 = red[t + 512] + red[t + 576] + red[t + 640] + red[t + 704];
    float b1 = red[t + 768] + red[t + 832] + red[t + 896] + red[t + 960];
    part_mu[blockIdx.x * 128 + 2 * t] = a0;
    part_mu[blockIdx.x * 128 + 2 * t + 1] = a1;
    part_m2[blockIdx.x * 128 + 2 * t] = b0;
    part_m2[blockIdx.x * 128 + 2 * t + 1] = b1;
  }
}

// ---------- reduce partials (one block per dim) -> scale/shift ----------
__global__ void k_bnred(const float* __restrict__ part_mu, const float* __restrict__ part_m2,
                        const float* __restrict__ gamma, const float* __restrict__ beta,
                        float* __restrict__ scale, float* __restrict__ shift) {
  __shared__ float smu[256], sm2[256];
  const int d = blockIdx.x;   // 128 blocks
  const int t = threadIdx.x;  // 256 threads
  float mu = 0.f, m2 = 0.f;
  for (int b = t; b < 1024; b += 256) {
    mu += part_mu[b * 128 + d];
    m2 += part_m2[b * 128 + d];
  }
  smu[t] = mu;
  sm2[t] = m2;
  __syncthreads();
  for (int s2 = 128; s2; s2 >>= 1) {
    if (t < s2) { smu[t] += smu[t + s2]; sm2[t] += sm2[t + s2]; }
    __syncthreads();
  }
  if (t == 0) {
    float muv = smu[0] / (float)kN;
    float var = sm2[0] / (float)kN - muv * muv;
    float inv = rsqrtf(var + 1e-5f);
    float sc = gamma[d] * inv;
    scale[d] = sc;
    shift[d] = beta[d] - muv * sc;
  }
}

// ---------- out = leakyrelu((a*v)*scale + shift), ALL NATURAL STREAMING ----------
__global__ __launch_bounds__(256) void k_out(
    const _Float16* __restrict__ v_nat, const float* __restrict__ a_nat,
    const float* __restrict__ scale, const float* __restrict__ shift,
    float* __restrict__ out) {
  const int t = threadIdx.x;
  const int d4 = (t & 31) * 4, rg = t >> 5;  // 32 lanes per row, 8 rows/block
  long n = (long)blockIdx.x * 8 + rg;
  if (n >= kN) return;
  float a = a_nat[n];
  f16x4 h = *(const f16x4*)(v_nat + n * 128 + d4);
  float4 sc = *(const float4*)(scale + d4);
  float4 sh = *(const float4*)(shift + d4);
  float4 o;
  o.x = fmaf(a * (float)h[0], sc.x, sh.x);
  o.y = fmaf(a * (float)h[1], sc.y, sh.y);
  o.z = fmaf(a * (float)h[2], sc.z, sh.z);
  o.w = fmaf(a * (float)h[3], sc.w, sh.w);
  o.x = o.x >= 0.f ? o.x : 0.2f * o.x;
  o.y = o.y >= 0.f ? o.y : 0.2f * o.y;
  o.z = o.z >= 0.f ? o.z : 0.2f * o.z;
  o.w = o.w >= 0.f ? o.w : 0.2f * o.w;
  *(float4*)(out + n * 128 + d4) = o;
}

extern "C" void kernel_launch(void* const* d_in, const int* in_sizes, int n_in,
                              void* d_out, int out_size, void* d_ws, size_t ws_size,
                              hipStream_t stream) {
  const float* x = (const float*)d_in[0];
  const int* cluster = (const int*)d_in[1];
  const float* Wv = (const float*)d_in[2];
  const float* bv = (const float*)d_in[3];
  const float* Wk = (const float*)d_in[4];
  const float* bk = (const float*)d_in[5];
  const float* Wq = (const float*)d_in[6];
  const float* bq = (const float*)d_in[7];
  const float* gamma = (const float*)d_in[8];
  const float* beta = (const float*)d_in[9];
  float* out = (float*)d_out;

  char* ws = (char*)d_ws;
  // layout (bytes)
  _Float16* Wc = (_Float16*)(ws + 0);        //    98,304
  float* bias_c = (float*)(ws + 98304);      //     1,536 -> 99,840
  int* hist = (int*)(ws + 99840);            //    40,000 -> 139,840 (zeroed)
  u32* m_enc = (u32*)(ws + 139840);          //    40,000 -> 179,840 (zeroed)
  float* s_sum = (float*)(ws + 179840);      //    40,000 -> 219,840 (zeroed)
  int* offs = (int*)(ws + 219840);           //    40,000 -> 259,840
  int* cur = (int*)(ws + 259840);            //    40,000 -> 299,840
  float* scale = (float*)(ws + 299840);      //       512 -> 300,352
  float* shift = (float*)(ws + 300352);      //       512 -> 300,864
  float* M_nat = (float*)(ws + 300864);      // 2,000,000 -> 2,300,864
  float* a_nat = (float*)(ws + 2300864);     // 2,000,000 -> 4,300,864
  int* order = (int*)(ws + 4300864);         // 2,000,000 -> 6,300,864
  int* csort = (int*)(ws + 6300864);         // 2,000,000 -> 8,300,864
  u32* q_enc = (u32*)(ws + 8300864);         // 5,120,000 -> 13,420,864 (zeroed in wcvt)
  float* w_all = (float*)(ws + 13420864);    // 5,120,000 -> 18,540,864
  float* part_mu = (float*)(ws + 18540864);  //   524,288 -> 19,065,152
  float* part_m2 = (float*)(ws + 19065152);  //   524,288 -> 19,589,440
  _Float16* WkT = (_Float16*)(ws + 19589440);    //  32,768 -> 19,622,208
  _Float16* v_nat = (_Float16*)(ws + 19622208);  // 128,000,000 -> 147,622,208

  // x_nat (f16, natural) lives in d_out scratch until k_out overwrites it
  _Float16* x_nat = (_Float16*)d_out;

  hipMemsetAsync(ws + 99840, 0, 219840 - 99840, stream);  // hist+m_enc+s_sum

  k_wcvt<<<192, 256, 0, stream>>>(Wv, Wk, Wq, bv, bk, bq, Wc, bias_c, WkT,
                                  cluster, hist, q_enc);
  k_vproj<<<(kN + 255) / 256, 256, 0, stream>>>(x, Wc, bias_c, v_nat, x_nat);
  k_scan<<<1, 256, 0, stream>>>(hist, offs, cur);
  k_scatter<<<(kN + 255) / 256, 256, 0, stream>>>(cluster, cur, order, csort);
  k_qproj<<<(kN + 255) / 256, 256, 0, stream>>>(x_nat, order, csort, Wc, bias_c,
                                                q_enc);
  k_wq<<<(kC + 63) / 64, 256, 0, stream>>>(q_enc, WkT, w_all);
  k_m<<<(int)((kN + 15) / 16), 256, 0, stream>>>(x_nat, w_all, cluster, M_nat,
                                                 m_enc);
  k_expsum<<<(kN + 255) / 256, 256, 0, stream>>>(M_nat, m_enc, cluster, s_sum);
  k_bnstats<<<1024, 256, 0, stream>>>(v_nat, M_nat, s_sum, cluster, a_nat,
                                      part_mu, part_m2);
  k_bnred<<<128, 256, 0, stream>>>(part_mu, part_m2, gamma, beta, scale, shift);
  k_out<<<(int)((kN + 7) / 8), 256, 0, stream>>>(v_nat, a_nat, scale, shift, out);
}

// Round 17
// 439.374 us; speedup vs baseline: 1.4714x; 1.4714x over previous
//
#include <hip/hip_runtime.h>

typedef unsigned int u32;
typedef float f32x4 __attribute__((ext_vector_type(4)));
typedef _Float16 f16x8 __attribute__((ext_vector_type(8)));
typedef _Float16 f16x4 __attribute__((ext_vector_type(4)));

static constexpr int kN = 500000;   // points
static constexpr int kC = 10000;    // clusters

// monotone float<->uint encoding so atomicMax(u32) == float max
__device__ __forceinline__ u32 fenc(float f) {
  int b = __float_as_int(f);
  return (b >= 0) ? ((u32)b | 0x80000000u) : ~((u32)b);
}
__device__ __forceinline__ float fdec(u32 u) {
  int b = (u & 0x80000000u) ? (int)(u & 0x7FFFFFFFu) : (int)(~u);
  return __int_as_float(b);
}

// ---------- W -> f16 concat + bias + WkT + histogram + q_enc zero (fused) ----------
__global__ void k_wcvt(const float* __restrict__ Wv, const float* __restrict__ Wk,
                       const float* __restrict__ Wq, const float* __restrict__ bv,
                       const float* __restrict__ bk, const float* __restrict__ bq,
                       _Float16* __restrict__ Wc, float* __restrict__ bias_c,
                       _Float16* __restrict__ WkT, const int* __restrict__ cluster,
                       int* __restrict__ hist, u32* __restrict__ q_enc) {
  const int i = blockIdx.x * blockDim.x + threadIdx.x;
  const long stride = (long)gridDim.x * blockDim.x;
  if (i < 384) bias_c[i] = (i < 128) ? bv[i] : (i < 256) ? bk[i - 128] : bq[i - 256];
  if (i < 128 * 128) {  // WkT[d][j] = Wk[j][d]
    int d = i >> 7, j = i & 127;
    WkT[i] = (_Float16)Wk[j * 128 + d];
  }
  if (i < 384 * 128) {
    int row = i >> 7;
    float f = (row < 128) ? Wv[i] : (row < 256) ? Wk[i - 128 * 128] : Wq[i - 256 * 128];
    Wc[i] = (_Float16)f;
  }
  // q_enc zero (encoded 0 == below -inf for the atomicMax)
  for (long e = i; e < (long)kC * 128; e += stride) q_enc[e] = 0u;
  // grid-stride histogram
  for (long n = i; n < kN; n += stride) atomicAdd(hist + cluster[n], 1);
}

// ---------- counting sort by cluster ----------
__global__ void k_scan(const int* __restrict__ hist, int* __restrict__ offs,
                       int* __restrict__ cur) {
  __shared__ int sh[256];
  const int t = threadIdx.x;  // 256 threads
  const int b0 = t * 40;
  const int e0 = (b0 + 40 < kC) ? b0 + 40 : kC;
  int s = 0;
  for (int i = b0; i < e0; ++i) s += hist[i];
  sh[t] = s;
  __syncthreads();
  for (int d = 1; d < 256; d <<= 1) {
    int v = (t >= d) ? sh[t - d] : 0;
    __syncthreads();
    sh[t] += v;
    __syncthreads();
  }
  int run = sh[t] - s;  // exclusive prefix
  for (int i = b0; i < e0; ++i) {
    offs[i] = run;
    cur[i] = run;
    run += hist[i];
  }
}

__global__ void k_scatter(const int* __restrict__ cluster, int* __restrict__ cur,
                          int* __restrict__ order, int* __restrict__ csort) {
  int n = blockIdx.x * blockDim.x + threadIdx.x;
  if (n < kN) {
    int c = cluster[n];
    int pos = atomicAdd(cur + c, 1);
    order[pos] = n;
    csort[pos] = c;
  }
}

// ---------- projections in SORTED domain (XCD-swizzled blocks) ----------
// Wave owns 64 sorted positions; gathers x rows (512B, L3-friendly); x (f16),
// v written STREAMING; qp reduced in LDS over cluster-runs -> atomicMax(q_enc).
// Measured: occupancy 2>3>4 (L3 thrash above 2); sorted-domain gather-proj
// beats natural-domain streaming-proj (r16: split/all-streaming = +206us).
__global__ __launch_bounds__(256, 2) void k_proj(
    const float* __restrict__ x, const int* __restrict__ order,
    const int* __restrict__ csort, const _Float16* __restrict__ Wc,
    const float* __restrict__ bias_c, _Float16* __restrict__ v_srt,
    _Float16* __restrict__ x_srt, u32* __restrict__ q_enc) {
  __shared__ _Float16 stg[4][64][70];  // pad 70: <=2-way on write/read/scan
  const int lane = threadIdx.x & 63, wid = threadIdx.x >> 6;
  const int g = lane >> 4, r = lane & 15;
  // bijective XCD-aware swizzle (m204): contiguous sorted spans per XCD.
  const int nwg = gridDim.x;
  const int qq = nwg >> 3, rr = nwg & 7;
  const int xcd = blockIdx.x & 7, sub = blockIdx.x >> 3;
  const int bid = (xcd < rr ? xcd * (qq + 1) : rr * (qq + 1) + (xcd - rr) * qq) + sub;
  const long pbase = (long)bid * 256 + wid * 64;

  long mypos = pbase + lane;
  if (mypos >= kN) mypos = kN - 1;
  const int myc = csort[mypos];

  // B-frags: x[order[pbase+p*16+r]][kk*32+8g+j]  (gathered 512B rows)
  f16x8 xf[4][4];
#pragma unroll
  for (int p = 0; p < 4; ++p) {
    long pos = pbase + p * 16 + r;
    if (pos >= kN) pos = kN - 1;
    const float* xp = x + (long)order[pos] * 128;
#pragma unroll
    for (int kk = 0; kk < 4; ++kk) {
      float4 f0 = *(const float4*)(xp + kk * 32 + g * 8);
      float4 f1 = *(const float4*)(xp + kk * 32 + g * 8 + 4);
      f16x8 h;
      h[0] = (_Float16)f0.x; h[1] = (_Float16)f0.y;
      h[2] = (_Float16)f0.z; h[3] = (_Float16)f0.w;
      h[4] = (_Float16)f1.x; h[5] = (_Float16)f1.y;
      h[6] = (_Float16)f1.z; h[7] = (_Float16)f1.w;
      xf[p][kk] = h;
    }
  }

  // stage + flush x_srt (f16, sorted, streaming) via wave-private LDS;
  // two 64-dim halves (stg holds 64 dims at a time).
#pragma unroll
  for (int h = 0; h < 2; ++h) {
#pragma unroll
    for (int p = 0; p < 4; ++p) {
#pragma unroll
      for (int q2 = 0; q2 < 2; ++q2)
        *(f16x8*)&stg[wid][p * 16 + r][q2 * 32 + g * 8] = xf[p][2 * h + q2];
    }
    const int off = h * 64;
#pragma unroll
    for (int s = 0; s < 8; ++s) {
      const int pl = 8 * s + (lane >> 3);
      const long pt = pbase + pl;
      if (pt < kN) {
        f16x8 val = *(const f16x8*)&stg[wid][pl][(lane & 7) * 8];
        *(f16x8*)(x_srt + pt * 128 + off + (lane & 7) * 8) = val;
      }
    }
  }

#pragma unroll
  for (int mg = 0; mg < 4; ++mg) {  // groups: v0,v1,qp0,qp1 (64 dims each)
#pragma unroll
    for (int mu = 0; mu < 4; ++mu) {
      const int mt = ((mg < 2) ? mg : mg + 2) * 4 + mu;  // skip Wk rows
      const _Float16* wrow = Wc + (mt * 16 + r) * 128;
      f16x8 wf[4];
#pragma unroll
      for (int kk = 0; kk < 4; ++kk)
        wf[kk] = *(const f16x8*)(wrow + kk * 32 + g * 8);
      float4 b4 = *(const float4*)(bias_c + mt * 16 + g * 4);
#pragma unroll
      for (int p = 0; p < 4; ++p) {
        f32x4 acc = {0.f, 0.f, 0.f, 0.f};
#pragma unroll
        for (int kk = 0; kk < 4; ++kk)
          acc = __builtin_amdgcn_mfma_f32_16x16x32_f16(wf[kk], xf[p][kk], acc, 0, 0, 0);
        f16x4 h;
        h[0] = (_Float16)(acc[0] + b4.x);
        h[1] = (_Float16)(acc[1] + b4.y);
        h[2] = (_Float16)(acc[2] + b4.z);
        h[3] = (_Float16)(acc[3] + b4.w);
        *(f16x4*)&stg[wid][p * 16 + r][mu * 16 + g * 4] = h;
      }
    }
    if (mg < 2) {
      // v flush: streaming 64 rows x 128B (contiguous in v_srt)
      const int off = (mg & 1) * 64;
#pragma unroll
      for (int s = 0; s < 8; ++s) {
        const int pl = 8 * s + (lane >> 3);
        const long pt = pbase + pl;
        if (pt < kN) {
          f16x8 val = *(const f16x8*)&stg[wid][pl][(lane & 7) * 8];
          *(f16x8*)(v_srt + pt * 128 + off + (lane & 7) * 8) = val;
        }
      }
    } else {
      // qp flush: per-dim run-max scan over the wave's 64 sorted points
      const int dg = (mg & 1) * 64 + lane;  // global q dim handled by this lane
      float m = -3.0e38f;
      int cprev = __shfl(myc, 0);
      for (int i = 0; i < 64; ++i) {
        int ci = __shfl(myc, i);
        if (ci != cprev) {  // wave-uniform branch
          atomicMax(q_enc + (long)cprev * 128 + dg, fenc(m));
          m = -3.0e38f;
          cprev = ci;
        }
        m = fmaxf(m, (float)stg[wid][i][lane]);
      }
      atomicMax(q_enc + (long)cprev * 128 + dg, fenc(m));
    }
  }
}

// ---------- w_all[c][j] = sum_d q[c][d] * Wk[d][j] = (Wk^T q_c)[j] ----------
__global__ __launch_bounds__(256) void k_wq(const u32* __restrict__ q_enc,
                                            const _Float16* __restrict__ WkT,
                                            float* __restrict__ w_all) {
  __shared__ float wt[4][16][132];
  const int lane = threadIdx.x & 63, wid = threadIdx.x >> 6;
  const int g = lane >> 4, r = lane & 15;
  const int c0 = blockIdx.x * 64 + wid * 16;

  // B-frags: B[k=kk*32+8g+j][col=r] = q[c0+r][kk*32+8g+j] (decode fenc)
  f16x8 qb[4];
  {
    int crow = c0 + r;
    if (crow >= kC) crow = kC - 1;
    const u32* qp = q_enc + (long)crow * 128;
#pragma unroll
    for (int kk = 0; kk < 4; ++kk) {
      uint4 u0 = *(const uint4*)(qp + kk * 32 + g * 8);
      uint4 u1 = *(const uint4*)(qp + kk * 32 + g * 8 + 4);
      f16x8 h;
      h[0] = (_Float16)fdec(u0.x); h[1] = (_Float16)fdec(u0.y);
      h[2] = (_Float16)fdec(u0.z); h[3] = (_Float16)fdec(u0.w);
      h[4] = (_Float16)fdec(u1.x); h[5] = (_Float16)fdec(u1.y);
      h[6] = (_Float16)fdec(u1.z); h[7] = (_Float16)fdec(u1.w);
      qb[kk] = h;
    }
  }
#pragma unroll
  for (int dt = 0; dt < 8; ++dt) {  // 8 output-dim tiles of 16 (j index)
    f32x4 acc = {0.f, 0.f, 0.f, 0.f};
#pragma unroll
    for (int kk = 0; kk < 4; ++kk) {
      // A[row=j-local=r][k=kk*32+8g+jj] = WkT[dt*16+r][kk*32+8g+jj]
      f16x8 af = *(const f16x8*)(WkT + (dt * 16 + r) * 128 + kk * 32 + g * 8);
      acc = __builtin_amdgcn_mfma_f32_16x16x32_f16(af, qb[kk], acc, 0, 0, 0);
    }
    // D[row=j-local=4g+jj][col=c-local=r] -> wt[c-local][j]
#pragma unroll
    for (int jj = 0; jj < 4; ++jj)
      wt[wid][r][dt * 16 + g * 4 + jj] = acc[jj];
  }
  // wave-private flush: 16 clusters x 512B streaming
#pragma unroll
  for (int s = 0; s < 8; ++s) {
    int row = s * 2 + (lane >> 5);
    int col = (lane & 31) * 4;
    int c = c0 + row;
    if (c < kC) {
      float4 v = *(const float4*)&wt[wid][row][col];
      *(float4*)(w_all + (long)c * 128 + col) = v;
    }
  }
}

// ---------- wave-per-cluster: M = x.w (STREAMING f16 x), softmax, BN partials ----------
__global__ __launch_bounds__(256) void k_attn(
    const _Float16* __restrict__ x_srt, const float* __restrict__ w_all,
    const _Float16* __restrict__ v_s, const int* __restrict__ offs,
    const int* __restrict__ hist, float* __restrict__ M_glob,
    float* __restrict__ a_srt, float* __restrict__ part_mu,
    float* __restrict__ part_m2) {
  __shared__ float Mw[4][512];
  const int lane = threadIdx.x & 63, wid = threadIdx.x >> 6;
  const int c = blockIdx.x * 4 + wid;
  if (c >= kC) return;
  const int start = offs[c], cnt = hist[c];
  if (cnt == 0) return;
  const int sub = lane >> 4, sl = lane & 15;
  const float* wp = w_all + (long)c * 128 + sl * 8;
  float4 w0 = *(const float4*)wp;
  float4 w1 = *(const float4*)(wp + 4);
  const bool fits = (cnt <= 512);
  float wmax = -3.0e38f;
  {
    int i = sub;
    // 2x unrolled: two independent row loads in flight per iteration
    for (; i + 4 < cnt; i += 8) {
      f16x8 hx0 = *(const f16x8*)(x_srt + (long)(start + i) * 128 + sl * 8);
      f16x8 hx1 = *(const f16x8*)(x_srt + (long)(start + i + 4) * 128 + sl * 8);
      float p0 = (float)hx0[0] * w0.x + (float)hx0[1] * w0.y +
                 (float)hx0[2] * w0.z + (float)hx0[3] * w0.w +
                 (float)hx0[4] * w1.x + (float)hx0[5] * w1.y +
                 (float)hx0[6] * w1.z + (float)hx0[7] * w1.w;
      float p1 = (float)hx1[0] * w0.x + (float)hx1[1] * w0.y +
                 (float)hx1[2] * w0.z + (float)hx1[3] * w0.w +
                 (float)hx1[4] * w1.x + (float)hx1[5] * w1.y +
                 (float)hx1[6] * w1.z + (float)hx1[7] * w1.w;
      p0 += __shfl_xor(p0, 1, 64);
      p1 += __shfl_xor(p1, 1, 64);
      p0 += __shfl_xor(p0, 2, 64);
      p1 += __shfl_xor(p1, 2, 64);
      p0 += __shfl_xor(p0, 4, 64);
      p1 += __shfl_xor(p1, 4, 64);
      p0 += __shfl_xor(p0, 8, 64);
      p1 += __shfl_xor(p1, 8, 64);
      if (sl == 0) {
        if (fits) {
          Mw[wid][i] = p0;
          Mw[wid][i + 4] = p1;
        } else {
          M_glob[start + i] = p0;
          M_glob[start + i + 4] = p1;
        }
      }
      wmax = fmaxf(wmax, fmaxf(p0, p1));
    }
    for (; i < cnt; i += 4) {
      f16x8 hx = *(const f16x8*)(x_srt + (long)(start + i) * 128 + sl * 8);
      float p = (float)hx[0] * w0.x + (float)hx[1] * w0.y +
                (float)hx[2] * w0.z + (float)hx[3] * w0.w +
                (float)hx[4] * w1.x + (float)hx[5] * w1.y +
                (float)hx[6] * w1.z + (float)hx[7] * w1.w;
      p += __shfl_xor(p, 1, 64);
      p += __shfl_xor(p, 2, 64);
      p += __shfl_xor(p, 4, 64);
      p += __shfl_xor(p, 8, 64);
      if (sl == 0) {
        if (fits) Mw[wid][i] = p;
        else M_glob[start + i] = p;
      }
      wmax = fmaxf(wmax, p);
    }
  }
  wmax = fmaxf(wmax, __shfl_xor(wmax, 16, 64));
  wmax = fmaxf(wmax, __shfl_xor(wmax, 32, 64));
  float lsum = 0.f;
  if (fits) {
    for (int i = lane; i < cnt; i += 64) {
      float e = __expf(Mw[wid][i] - wmax);
      Mw[wid][i] = e;
      lsum += e;
    }
  } else {
    asm volatile("s_waitcnt vmcnt(0)" ::: "memory");
    for (int i = lane; i < cnt; i += 64) {
      float e = __expf(M_glob[start + i] - wmax);
      M_glob[start + i] = e;
      lsum += e;
    }
  }
#pragma unroll
  for (int off = 1; off < 64; off <<= 1) lsum += __shfl_xor(lsum, off, 64);
  const float inv = 1.f / lsum;
  if (fits) {
    for (int i = lane; i < cnt; i += 64) a_srt[start + i] = Mw[wid][i] * inv;
  } else {
    asm volatile("s_waitcnt vmcnt(0)" ::: "memory");
    for (int i = lane; i < cnt; i += 64) a_srt[start + i] = M_glob[start + i] * inv;
  }
  // phase 4: BN partials (y = a*v) over this cluster's v rows (streaming)
  float s0[8], s1[8];
#pragma unroll
  for (int j = 0; j < 8; ++j) { s0[j] = 0.f; s1[j] = 0.f; }
  if (fits) {
    for (int i = sub; i < cnt; i += 4) {
      float a = Mw[wid][i] * inv;
      f16x8 h = *(const f16x8*)(v_s + (long)(start + i) * 128 + sl * 8);
#pragma unroll
      for (int j = 0; j < 8; ++j) {
        float y = a * (float)h[j];
        s0[j] += y;
        s1[j] += y * y;
      }
    }
  } else {
    asm volatile("s_waitcnt vmcnt(0)" ::: "memory");
    for (int i = sub; i < cnt; i += 4) {
      float a = M_glob[start + i] * inv;
      f16x8 h = *(const f16x8*)(v_s + (long)(start + i) * 128 + sl * 8);
#pragma unroll
      for (int j = 0; j < 8; ++j) {
        float y = a * (float)h[j];
        s0[j] += y;
        s1[j] += y * y;
      }
    }
  }
#pragma unroll
  for (int j = 0; j < 8; ++j) {
    s0[j] += __shfl_xor(s0[j], 16, 64);
    s0[j] += __shfl_xor(s0[j], 32, 64);
    s1[j] += __shfl_xor(s1[j], 16, 64);
    s1[j] += __shfl_xor(s1[j], 32, 64);
  }
  if (sub == 0) {
    float4 m0 = {s0[0], s0[1], s0[2], s0[3]};
    float4 m1 = {s0[4], s0[5], s0[6], s0[7]};
    float4 p0 = {s1[0], s1[1], s1[2], s1[3]};
    float4 p1 = {s1[4], s1[5], s1[6], s1[7]};
    *(float4*)(part_mu + (long)c * 128 + sl * 8) = m0;
    *(float4*)(part_mu + (long)c * 128 + sl * 8 + 4) = m1;
    *(float4*)(part_m2 + (long)c * 128 + sl * 8) = p0;
    *(float4*)(part_m2 + (long)c * 128 + sl * 8 + 4) = p1;
  }
}

// ---------- fused: reduce per-cluster partials -> bn_acc -> scale/shift ----------
__global__ void k_bnred(const float* __restrict__ part_mu, const float* __restrict__ part_m2,
                        const int* __restrict__ hist, float* __restrict__ bn_acc,
                        int* __restrict__ done_ctr, const float* __restrict__ gamma,
                        const float* __restrict__ beta, float* __restrict__ scale,
                        float* __restrict__ shift) {
  const int t = threadIdx.x;        // 256
  const int h = t >> 7, d = t & 127;
  const float* part = h ? part_m2 : part_mu;
  const int c0 = blockIdx.x * 125;  // 80 blocks
  const int c1 = (c0 + 125 < kC) ? c0 + 125 : kC;
  float s = 0.f;
  for (int c = c0; c < c1; ++c)
    if (hist[c] > 0) s += part[(long)c * 128 + d];
  atomicAdd(bn_acc + h * 128 + d, s);
  __threadfence();  // publish bn_acc before signaling
  __syncthreads();
  __shared__ int is_last;
  if (t == 0) is_last = (atomicAdd(done_ctr, 1) == gridDim.x - 1);
  __syncthreads();
  if (is_last && t < 128) {  // last block finalizes scale/shift
    float mu = bn_acc[t] / (float)kN;
    float var = bn_acc[128 + t] / (float)kN - mu * mu;
    float iv = rsqrtf(var + 1e-5f);
    float sc = gamma[t] * iv;
    scale[t] = sc;
    shift[t] = beta[t] - mu * sc;
  }
}

// ---------- out[order[i]] = leakyrelu((a*v)*scale + shift) ----------
__global__ __launch_bounds__(256) void k_out(
    const _Float16* __restrict__ v_s, const float* __restrict__ a_srt,
    const int* __restrict__ order, const float* __restrict__ scale,
    const float* __restrict__ shift, float* __restrict__ out) {
  const int t = threadIdx.x;
  const int d4 = (t & 31) * 4, rg = t >> 5;  // 32 lanes per row, 8 rows/block
  long i = (long)blockIdx.x * 8 + rg;
  if (i >= kN) return;
  int n = order[i];
  float a = a_srt[i];
  f16x4 h = *(const f16x4*)(v_s + i * 128 + d4);
  float4 sc = *(const float4*)(scale + d4);
  float4 sh = *(const float4*)(shift + d4);
  float4 o;
  o.x = fmaf(a * (float)h[0], sc.x, sh.x);
  o.y = fmaf(a * (float)h[1], sc.y, sh.y);
  o.z = fmaf(a * (float)h[2], sc.z, sh.z);
  o.w = fmaf(a * (float)h[3], sc.w, sh.w);
  o.x = o.x >= 0.f ? o.x : 0.2f * o.x;
  o.y = o.y >= 0.f ? o.y : 0.2f * o.y;
  o.z = o.z >= 0.f ? o.z : 0.2f * o.z;
  o.w = o.w >= 0.f ? o.w : 0.2f * o.w;
  *(float4*)(out + (long)n * 128 + d4) = o;
}

extern "C" void kernel_launch(void* const* d_in, const int* in_sizes, int n_in,
                              void* d_out, int out_size, void* d_ws, size_t ws_size,
                              hipStream_t stream) {
  const float* x = (const float*)d_in[0];
  const int* cluster = (const int*)d_in[1];
  const float* Wv = (const float*)d_in[2];
  const float* bv = (const float*)d_in[3];
  const float* Wk = (const float*)d_in[4];
  const float* bk = (const float*)d_in[5];
  const float* Wq = (const float*)d_in[6];
  const float* bq = (const float*)d_in[7];
  const float* gamma = (const float*)d_in[8];
  const float* beta = (const float*)d_in[9];
  float* out = (float*)d_out;

  char* ws = (char*)d_ws;
  // layout (bytes)
  _Float16* Wc = (_Float16*)(ws + 0);        //    98,304
  float* bias_c = (float*)(ws + 98304);      //     1,536 -> 99,840
  int* hist = (int*)(ws + 99840);            //    40,000 -> 139,840 (zeroed)
  float* bn_acc = (float*)(ws + 139840);     //     1,024 -> 140,864 (zeroed)
  int* done_ctr = (int*)(ws + 140864);       //        64 -> 140,928 (zeroed)
  int* offs = (int*)(ws + 140928);           //    40,000 -> 180,928
  int* cur = (int*)(ws + 180928);            //    40,000 -> 220,928
  float* scale = (float*)(ws + 220928);      //       512 -> 221,440
  float* shift = (float*)(ws + 221440);      //       512 -> 221,952
  float* M_glob = (float*)(ws + 221952);     // 2,000,000 -> 2,221,952
  float* a_srt = (float*)(ws + 2221952);     // 2,000,000 -> 4,221,952
  int* order = (int*)(ws + 4221952);         // 2,000,000 -> 6,221,952
  int* csort = (int*)(ws + 6221952);         // 2,000,000 -> 8,221,952
  u32* q_enc = (u32*)(ws + 8221952);         // 5,120,000 -> 13,341,952 (zeroed in k_wcvt)
  float* w_all = (float*)(ws + 13341952);    // 5,120,000 -> 18,461,952
  float* part_mu = (float*)(ws + 18461952);  // 5,120,000 -> 23,581,952
  float* part_m2 = (float*)(ws + 23581952);  // 5,120,000 -> 28,701,952
  _Float16* WkT = (_Float16*)(ws + 28701952);    //  32,768 -> 28,734,720
  _Float16* v_srt = (_Float16*)(ws + 28734720);  // 128,000,000 -> 156,734,720

  // x_srt (f16, sorted) lives in d_out scratch until k_out overwrites it
  _Float16* x_srt = (_Float16*)d_out;

  hipMemsetAsync(ws + 99840, 0, 140928 - 99840, stream);  // hist+bn_acc+done

  k_wcvt<<<192, 256, 0, stream>>>(Wv, Wk, Wq, bv, bk, bq, Wc, bias_c, WkT,
                                  cluster, hist, q_enc);
  k_scan<<<1, 256, 0, stream>>>(hist, offs, cur);
  k_scatter<<<(kN + 255) / 256, 256, 0, stream>>>(cluster, cur, order, csort);
  k_proj<<<(kN + 255) / 256, 256, 0, stream>>>(x, order, csort, Wc, bias_c,
                                               v_srt, x_srt, q_enc);
  k_wq<<<(kC + 63) / 64, 256, 0, stream>>>(q_enc, WkT, w_all);
  k_attn<<<(kC + 3) / 4, 256, 0, stream>>>(x_srt, w_all, v_srt, offs, hist,
                                           M_glob, a_srt, part_mu, part_m2);
  k_bnred<<<80, 256, 0, stream>>>(part_mu, part_m2, hist, bn_acc, done_ctr,
                                  gamma, beta, scale, shift);
  k_out<<<(int)((kN + 7) / 8), 256, 0, stream>>>(v_srt, a_srt, order, scale,
                                                 shift, out);
}